// Round 4
// baseline (85.836 us; speedup 1.0000x reference)
//
#include <hip/hip_runtime.h>
#include <hip/hip_bf16.h>
#include <math.h>

#define B_ 32
#define N_ 16384
#define D_ 128
#define NEG_SLOPE 0.2f
#define CHUNKS 16      // 512 blocks
#define TILES 16       // 64-row tiles per chunk

typedef __attribute__((ext_vector_type(8))) short short8;
typedef __attribute__((ext_vector_type(4))) float f32x4;

__device__ __forceinline__ unsigned pk2(float lo, float hi) {
    union { __hip_bfloat162 b; unsigned u; } t;
    t.b = __float22bfloat162_rn(make_float2(lo, hi));
    return t.u;
}
__device__ __forceinline__ short8 cvt8(float4 x, float4 y) {
    union { unsigned u[4]; short8 s; } r;
    r.u[0] = pk2(x.x, x.y); r.u[1] = pk2(x.z, x.w);
    r.u[2] = pk2(y.x, y.y); r.u[3] = pk2(y.z, y.w);
    return r.s;
}

// ---- fused main: hq + h_key GEMM + logits + online softmax ----
// Wk col-split across 4 waves (bfrag 32 VGPR); key staged via plain
// global_load -> regs -> bf16 ds_write (ring-2 LDS, XOR swizzle);
// raw s_barrier + lgkmcnt(0) only (vmcnt alive across barriers).
__global__ __launch_bounds__(256, 3) void
main_kernel(const float* __restrict__ query, const float* __restrict__ key,
            const float* __restrict__ Wq, const float* __restrict__ Wk,
            const float* __restrict__ Wa,
            float* __restrict__ logits, float* __restrict__ part) {
    __shared__ unsigned short kt[2][64 * D_];   // 2 x 16 KB bf16 swizzled tiles
    __shared__ float plds[4][64];               // per-wave partial logits

    const int b = blockIdx.y, chunk = blockIdx.x;
    const int tid = threadIdx.x;
    const int w = tid >> 6, lane = tid & 63, ln = lane & 15, g = lane >> 4;
    const int n0 = chunk * (N_ / CHUNKS);
    const int hcol0 = w * 32 + ln;              // this wave's H-col base (+cf*16)

    // ---- Wk fragments: only this wave's 32 cols (32 VGPRs) ----
    short8 bfrag[2][4];
#pragma unroll
    for (int cf = 0; cf < 2; ++cf) {
        const float* wp = Wk + (size_t)(hcol0 + cf * 16) * D_;
#pragma unroll
        for (int kk = 0; kk < 4; ++kk) {
            const float4* p = (const float4*)(wp + kk * 32 + g * 8);
            bfrag[cf][kk] = cvt8(p[0], p[1]);
        }
    }
    // ---- hq, Wa for this wave's cols ----
    float hq_r[2], wa_r[2];
    {
        const float4* qv = (const float4*)(query + (size_t)b * D_);
#pragma unroll
        for (int cf = 0; cf < 2; ++cf) {
            const float4* wv = (const float4*)(Wq + (size_t)(hcol0 + cf * 16) * D_ + g * 32);
            float s = 0.f;
#pragma unroll
            for (int u = 0; u < 8; ++u) {
                float4 wq = wv[u], qq = qv[g * 8 + u];
                s = fmaf(wq.x, qq.x, s); s = fmaf(wq.y, qq.y, s);
                s = fmaf(wq.z, qq.z, s); s = fmaf(wq.w, qq.w, s);
            }
            s += __shfl_xor(s, 16);
            s += __shfl_xor(s, 32);
            hq_r[cf] = s;
            wa_r[cf] = Wa[hcol0 + cf * 16];
        }
    }

    float m_w = -1e30f, l_w = 0.f, accl0 = 0.f, accl1 = 0.f;

    const float* kbase = key + ((size_t)b * N_ + n0) * D_;
    const int srow = w * 16 + (lane >> 2);      // staging row within tile
    const int scol = (lane & 3) * 4;            // staging col (floats)
    float4 sregs[8];

    auto issue = [&](int tt) {
        const float* src = kbase + (size_t)(tt * 64 + srow) * D_ + scol;
#pragma unroll
        for (int k = 0; k < 8; ++k)
            sregs[k] = *(const float4*)(src + k * 16);
    };
    auto write_tile = [&](int buf) {
        char* base = (char*)&kt[buf][0];
#pragma unroll
        for (int k = 0; k < 8; ++k) {
            unsigned a = (unsigned)(srow * 256 + (lane & 3) * 8 + k * 32) ^
                         ((unsigned)(srow & 7) << 4);
            uint2 pk;
            pk.x = pk2(sregs[k].x, sregs[k].y);
            pk.y = pk2(sregs[k].z, sregs[k].w);
            *(uint2*)(base + a) = pk;
        }
    };

    issue(0);
    write_tile(0);      // compiler inserts vmcnt wait before use
    issue(1);

    for (int t = 0; t < TILES; ++t) {
        if (t + 1 < TILES) {
            write_tile((t + 1) & 1);            // sregs -> bf16 LDS
            if (t + 2 < TILES) issue(t + 2);    // loads fly across barriers
        }
        asm volatile("s_waitcnt lgkmcnt(0)" ::: "memory");
        __builtin_amdgcn_s_barrier();           // tile t ready for all waves

        // ---- GEMM: 64 rows x this wave's 32 cols ----
        f32x4 acc[4][2] = {};
        const char* base = (const char*)&kt[t & 1][0];
#pragma unroll
        for (int kk = 0; kk < 4; ++kk) {
#pragma unroll
            for (int rf = 0; rf < 4; ++rf) {
                int row = rf * 16 + ln;
                short8 a = *(const short8*)(base +
                    ((unsigned)(row * 256 + kk * 64 + g * 16) ^ ((unsigned)(row & 7) << 4)));
                acc[rf][0] = __builtin_amdgcn_mfma_f32_16x16x32_bf16(a, bfrag[0][kk], acc[rf][0], 0, 0, 0);
                acc[rf][1] = __builtin_amdgcn_mfma_f32_16x16x32_bf16(a, bfrag[1][kk], acc[rf][1], 0, 0, 0);
            }
        }

        // ---- partial logits over this wave's cols; reduce over ln ----
#pragma unroll
        for (int rf = 0; rf < 4; ++rf) {
            f32x4 lp;
#pragma unroll
            for (int j = 0; j < 4; ++j) {
                float v0 = hq_r[0] + acc[rf][0][j];
                v0 = (v0 > 0.f) ? v0 : NEG_SLOPE * v0;
                float v1 = hq_r[1] + acc[rf][1][j];
                v1 = (v1 > 0.f) ? v1 : NEG_SLOPE * v1;
                float s = fmaf(v0, wa_r[0], v1 * wa_r[1]);
                s += __shfl_xor(s, 1);
                s += __shfl_xor(s, 2);
                s += __shfl_xor(s, 4);
                s += __shfl_xor(s, 8);
                lp[j] = s;
            }
            if (ln == 0)
                *(f32x4*)&plds[w][rf * 16 + g * 4] = lp;
        }
        asm volatile("s_waitcnt lgkmcnt(0)" ::: "memory");
        __builtin_amdgcn_s_barrier();           // partials visible

        // ---- full logits = sum of 4 wave-partials; online softmax ----
        f32x4 p[4];
        float mt = -1e30f;
#pragma unroll
        for (int rf = 0; rf < 4; ++rf) {
            f32x4 lg = *(const f32x4*)&plds[0][rf * 16 + g * 4];
#pragma unroll
            for (int ww = 1; ww < 4; ++ww) {
                f32x4 q = *(const f32x4*)&plds[ww][rf * 16 + g * 4];
                lg[0] += q[0]; lg[1] += q[1]; lg[2] += q[2]; lg[3] += q[3];
            }
            p[rf] = lg;
            mt = fmaxf(mt, fmaxf(fmaxf(lg[0], lg[1]), fmaxf(lg[2], lg[3])));
        }
        if (w == 3 && ln == 0) {                // one wave stores logits
            int nb = n0 + t * 64 + g * 4;
#pragma unroll
            for (int rf = 0; rf < 4; ++rf)
                *(f32x4*)&logits[(size_t)b * N_ + nb + rf * 16] = p[rf];
        }
        mt = fmaxf(mt, __shfl_xor(mt, 16));
        mt = fmaxf(mt, __shfl_xor(mt, 32));
        float m_new = fmaxf(m_w, mt);
        float corr = __expf(m_w - m_new);
        l_w *= corr; accl0 *= corr; accl1 *= corr;
#pragma unroll
        for (int rf = 0; rf < 4; ++rf) {
#pragma unroll
            for (int j = 0; j < 4; ++j) {
                float pe = __expf(p[rf][j] - m_new);
                l_w += pe;                       // lane covers its 16 rows (g fixed)
                accl0 = fmaf(pe, acc[rf][0][j], accl0);
                accl1 = fmaf(pe, acc[rf][1][j], accl1);
            }
        }
        m_w = m_new;
    }

    // reduce over g (rows were split by g); ln lanes are distinct cols
    l_w += __shfl_xor(l_w, 16);  l_w += __shfl_xor(l_w, 32);
    accl0 += __shfl_xor(accl0, 16); accl0 += __shfl_xor(accl0, 32);
    accl1 += __shfl_xor(accl1, 16); accl1 += __shfl_xor(accl1, 32);

    float* pp = part + ((size_t)b * CHUNKS + chunk) * 132;
    if (g == 0) {
        pp[2 + w * 32 + ln] = accl0;
        pp[2 + w * 32 + 16 + ln] = accl1;
    }
    if (tid == 0) { pp[0] = m_w; pp[1] = l_w; }
}

// ---- fused finish + e ----
__global__ __launch_bounds__(256) void
finish_e_kernel(const float* __restrict__ part, const float* __restrict__ logits,
                float* __restrict__ out) {
    const int b = blockIdx.y, s = blockIdx.x, t = threadIdx.x;
    float mb = -1e30f;
#pragma unroll
    for (int c = 0; c < CHUNKS; ++c)
        mb = fmaxf(mb, part[((size_t)b * CHUNKS + c) * 132]);
    float lb = 0.f;
#pragma unroll
    for (int c = 0; c < CHUNKS; ++c) {
        const float* pp = part + ((size_t)b * CHUNKS + c) * 132;
        lb = fmaf(pp[1], __expf(pp[0] - mb), lb);
    }
    if (s == 0 && t < D_) {
        float ac = 0.f;
#pragma unroll
        for (int c = 0; c < CHUNKS; ++c) {
            const float* pp = part + ((size_t)b * CHUNKS + c) * 132;
            ac = fmaf(pp[2 + t], __expf(pp[0] - mb), ac);
        }
        float sc = ac / lb;
        out[b * D_ + t] = (sc > 0.f) ? sc : expm1f(sc);
    }
    float inv = 1.f / lb;
    int n4 = s * 1024 + t * 4;
    float4 lg = *(const float4*)&logits[(size_t)b * N_ + n4];
    float4 e;
    e.x = __expf(lg.x - mb) * inv;
    e.y = __expf(lg.y - mb) * inv;
    e.z = __expf(lg.z - mb) * inv;
    e.w = __expf(lg.w - mb) * inv;
    *(float4*)&out[(size_t)B_ * D_ + (size_t)b * N_ + n4] = e;
}

extern "C" void kernel_launch(void* const* d_in, const int* in_sizes, int n_in,
                              void* d_out, int out_size, void* d_ws, size_t ws_size,
                              hipStream_t stream) {
    const float* query = (const float*)d_in[0];
    const float* key   = (const float*)d_in[1];
    const float* Wq    = (const float*)d_in[2];
    const float* Wk    = (const float*)d_in[3];
    const float* Wa    = (const float*)d_in[4];
    float* out = (float*)d_out;

    float* ws     = (float*)d_ws;
    float* logits = ws;                                   // B*N
    float* part   = logits + (size_t)B_ * N_;             // 32*16*132

    main_kernel<<<dim3(CHUNKS, B_), dim3(256), 0, stream>>>(query, key, Wq, Wk, Wa, logits, part);
    finish_e_kernel<<<dim3(16, B_), dim3(256), 0, stream>>>(part, logits, out);
}